// Round 5
// baseline (245.732 us; speedup 1.0000x reference)
//
#include <hip/hip_runtime.h>
#include <hip/hip_bf16.h>

// MC3DAD kNN(k=5) covariance-trace curvature. B=8, N=4096, f32.
// Round 5: exact pruned search via x-sorted strips.
//   K1: per batch, counting-sort points into 128 x-strips -> ws
//       (sorted float4 {x,y,z,|p|^2} + orig idx u16 + strip table).
//   K2: 1024 single-wave blocks; each wave = 32 consecutive SORTED queries
//       (2 lanes/query, even/odd candidate parity). Strips scanned outward
//       from the wave's base strips; lane skips strip s only when
//       gap(s)^2 >= tau + 1e-3, tau = exact upper bound on final 5th-best
//       d2 (seeded from 5 sorted-neighbors incl. self; tightened by exact
//       drains). Top-5 kept as packed u64 (bits(max(dd,0))<<32 | orig_idx)
//       via strict-< insertion network => scan-order independent (counting
//       sort's nondeterministic within-strip order cannot change output).
//       Fast fmaf filter + always-write LDS append + exact-tree drains are
//       the r3-proven machinery (absmax 0.0).
//   K3: r1's proven curvature normalization, in-place on d_out.

typedef unsigned long long ull;
typedef unsigned short u16;
typedef unsigned int u32;

constexpr int   N_PTS  = 4096;
constexpr int   BATCH  = 8;
constexpr int   KNN    = 5;
constexpr int   NSTRIP = 128;
constexpr float XMIN   = -5.0f;
constexpr float STRIPW = 0.078125f;    // 10/128, exact in fp32
constexpr float INVW   = 12.8f;
constexpr int   CH     = 128;          // staging chunk (candidates)
constexpr int   KSLOT  = 16;           // per-lane append slots
constexpr int   TRIG   = 12;           // mid-chunk drain trigger
constexpr float FILT_MARGIN = 1e-4f;   // fast-filter false-reject slack
constexpr float STRIP_SLACK = 1e-3f;   // strip-skip slack (>> fp32 expansion err)

__device__ __forceinline__ ull umin64(ull a, ull b) { return a < b ? a : b; }
__device__ __forceinline__ ull umax64(ull a, ull b) { return a < b ? b : a; }

// Merge two ascending sorted 5-lists (u64 lex keys) -> ascending bottom-5.
__device__ __forceinline__ void merge5(ull a[KNN], const ull b[KNN])
{
    const ull r0 = umin64(a[0], b[0]);
    const ull r1 = umin64(umin64(a[1], b[1]), umax64(a[0], b[0]));
    const ull r2 = umin64(umin64(a[2], b[2]),
                          umin64(umax64(a[1], b[0]), umax64(a[0], b[1])));
    const ull r3 = umin64(umin64(a[3], b[3]),
                   umin64(umax64(a[2], b[0]),
                   umin64(umax64(a[1], b[1]), umax64(a[0], b[2]))));
    const ull r4 = umin64(umin64(a[4], b[4]),
                   umin64(umin64(umax64(a[3], b[0]), umax64(a[2], b[1])),
                          umin64(umax64(a[1], b[2]), umax64(a[0], b[3]))));
    a[0] = r0; a[1] = r1; a[2] = r2; a[3] = r3; a[4] = r4;
}

// ---------------- K1: counting sort into x-strips ----------------
__global__ __launch_bounds__(256)
void build_kernel(const float* __restrict__ pcd, float4* __restrict__ spts,
                  u16* __restrict__ sidx, u32* __restrict__ table)
{
    __shared__ u32 hist[NSTRIP];
    __shared__ u32 cur[NSTRIP];
    const int b = blockIdx.x;
    const int t = threadIdx.x;
    const float* __restrict__ batch = pcd + (size_t)b * N_PTS * 3;

    if (t < NSTRIP) hist[t] = 0;
    __syncthreads();

    float px[16], py[16], pz[16]; int ps[16];
    #pragma unroll
    for (int i = 0; i < 16; ++i) {
        const int p = t + i * 256;
        const float x = batch[p * 3 + 0];
        const float y = batch[p * 3 + 1];
        const float z = batch[p * 3 + 2];
        px[i] = x; py[i] = y; pz[i] = z;
        int s = (int)floorf((x - XMIN) * INVW);
        s = s < 0 ? 0 : (s > NSTRIP - 1 ? NSTRIP - 1 : s);
        ps[i] = s;
        atomicAdd(&hist[s], 1u);
    }
    __syncthreads();
    // inclusive scan over 128 bins
    for (int off = 1; off < NSTRIP; off <<= 1) {
        u32 v = 0;
        if (t < NSTRIP && t >= off) v = hist[t - off];
        __syncthreads();
        if (t < NSTRIP) hist[t] += v;
        __syncthreads();
    }
    if (t < NSTRIP) {
        const u32 st = (t == 0) ? 0u : hist[t - 1];
        cur[t] = st;
        table[(size_t)b * 130 + t] = st;
    }
    if (t == 0) table[(size_t)b * 130 + NSTRIP] = hist[NSTRIP - 1];  // 4096
    __syncthreads();

    float4* __restrict__ bp = spts + (size_t)b * N_PTS;
    u16*    __restrict__ bi = sidx + (size_t)b * N_PTS;
    #pragma unroll
    for (int i = 0; i < 16; ++i) {
        const int p = t + i * 256;
        const u32 pos = atomicAdd(&cur[ps[i]], 1u);
        const float x = px[i], y = py[i], z = pz[i];
        const float w = __fadd_rn(__fadd_rn(__fmul_rn(x, x), __fmul_rn(y, y)),
                                  __fmul_rn(z, z));            // exact |p|^2 tree
        bp[pos] = make_float4(x, y, z, w);
        bi[pos] = (u16)p;
    }
}

// ---------------- K2: strip-pruned exact kNN + trace ----------------
__global__ __launch_bounds__(64, 4)
void knn_kernel(const float* __restrict__ pcd, const float4* __restrict__ spts,
                const u16* __restrict__ sidx, const u32* __restrict__ table,
                float* __restrict__ trace_out)
{
    __shared__ float4 cpts[CH];
    __shared__ u16    cidx[CH];
    __shared__ u16    buf[KSLOT * 64];

    const int b    = blockIdx.y;
    const int lane = threadIdx.x;          // 0..63
    const int pr   = lane & 1;             // candidate parity
    const int qi   = lane >> 1;            // 0..31
    const int qs   = blockIdx.x * 32 + qi; // sorted query position

    const float4* __restrict__ bp    = spts  + (size_t)b * N_PTS;
    const u16*    __restrict__ bi    = sidx  + (size_t)b * N_PTS;
    const u32*    __restrict__ bt    = table + (size_t)b * 130;
    const float*  __restrict__ batch = pcd   + (size_t)b * N_PTS * 3;

    const float4 q4 = bp[qs];
    const float qx = q4.x, qy = q4.y, qz = q4.z, qw = q4.w;

    // ---- seed tau: exact dd of 5 sorted-neighbors (incl. self => >= 0) ----
    float tau = 0.0f;
    {
        int w0 = qs - 2;
        w0 = w0 < 0 ? 0 : (w0 > N_PTS - 5 ? N_PTS - 5 : w0);
        #pragma unroll
        for (int i = 0; i < 5; ++i) {
            const float4 c = bp[w0 + i];
            const float dot = __fadd_rn(__fadd_rn(__fmul_rn(qx, c.x),
                                                  __fmul_rn(qy, c.y)),
                                        __fmul_rn(qz, c.z));
            const float dd  = __fsub_rn(__fadd_rn(qw, c.w), __fmul_rn(2.0f, dot));
            tau = fmaxf(tau, dd);
        }
    }

    ull key[KNN];
    #pragma unroll
    for (int r = 0; r < KNN; ++r) key[r] = 0x7f800000ffffffffULL;  // (+inf, ~0)

    u16* lanebuf = buf + lane;
    int cnt = 0;

    // exact-tree drain of appended candidates from the staged chunk
    auto drain = [&]() {
        for (int j = 0; __any(j < cnt); ++j) {
            if (j < cnt) {
                const int l = lanebuf[j * 64];
                const float4 c = cpts[l];
                const float dot = __fadd_rn(__fadd_rn(__fmul_rn(qx, c.x),
                                                      __fmul_rn(qy, c.y)),
                                            __fmul_rn(qz, c.z));
                const float dd  = __fsub_rn(__fadd_rn(qw, c.w),
                                            __fmul_rn(2.0f, dot));
                const float ddk = fmaxf(dd, 0.0f);           // ref: max(d2,0)
                ull a = ((ull)__float_as_uint(ddk) << 32) | (u32)cidx[l];
                #pragma unroll
                for (int p = 0; p < KNN; ++p) {              // strict-< insert
                    const ull lo = umin64(a, key[p]);
                    const ull hi = umax64(a, key[p]);
                    key[p] = lo; a = hi;
                }
            }
        }
        cnt = 0;
        tau = fminf(tau, __uint_as_float((u32)(key[KNN - 1] >> 32)));
    };

    auto scan_strip = [&](int s) {
        const u32 st = bt[s], en = bt[s + 1];
        for (u32 c0 = st; c0 < en; c0 += CH) {
            const int m = min((int)(en - c0), CH);
            if (lane < m)      { cpts[lane]      = bp[c0 + lane];
                                 cidx[lane]      = bi[c0 + lane]; }
            if (lane + 64 < m) { cpts[lane + 64] = bp[c0 + lane + 64];
                                 cidx[lane + 64] = bi[c0 + lane + 64]; }
            __syncthreads();
            float tauf = tau - qw + FILT_MARGIN;
            for (int j = pr; j < m; j += 2) {
                const float4 c = cpts[j];
                const float t2 = fmaf(-2.0f,
                                      fmaf(qx, c.x, fmaf(qy, c.y, qz * c.z)),
                                      c.w);
                const bool keep = t2 < tauf;
                lanebuf[cnt * 64] = (u16)j;                  // always-write
                cnt += keep ? 1 : 0;
                if (__any(cnt > TRIG)) { drain(); tauf = tau - qw + FILT_MARGIN; }
            }
            drain();                                          // before restage
            tau = fminf(tau, __shfl_xor(tau, 1));             // pair tau share
            __syncthreads();
        }
    };

    // ---- strip walk: base range, then alternate outward with need tests ----
    int myStrip = (int)floorf((qx - XMIN) * INVW);
    myStrip = myStrip < 0 ? 0 : (myStrip > NSTRIP - 1 ? NSTRIP - 1 : myStrip);
    const int sLo = __builtin_amdgcn_readlane(myStrip, 0);    // sorted => min
    const int sHi = __builtin_amdgcn_readlane(myStrip, 63);   // sorted => max
    for (int s = sLo; s <= sHi; ++s) scan_strip(s);

    int sR = sHi + 1, sL = sLo - 1;
    while (true) {
        const float lim = tau + STRIP_SLACK;
        bool nR = false, nL = false;
        if (sR <= NSTRIP - 1) {
            const float gap = (XMIN + sR * STRIPW) - qx;      // left edge of sR
            nR = gap * gap < lim;
        }
        if (sL >= 0) {
            const float gap = qx - (XMIN + (sL + 1) * STRIPW); // right edge of sL
            nL = gap * gap < lim;
        }
        const bool aR = __any(nR), aL = __any(nL);
        if (!aR && !aL) break;
        if (aR) { scan_strip(sR); ++sR; }
        if (aL) { scan_strip(sL); --sL; }
    }

    // ---- pair merge (even/odd candidate halves) ----
    {
        ull o[KNN];
        #pragma unroll
        for (int r = 0; r < KNN; ++r) o[r] = __shfl_xor(key[r], 1);
        merge5(key, o);
    }

    // ---- epilogue on even lane: sqrt-rerank, centroid, cov trace ----
    if (pr == 0) {
        ull k2[KNN];
        #pragma unroll
        for (int r = 0; r < KNN; ++r) {
            const float dd = __uint_as_float((u32)(key[r] >> 32));
            const float dist = __fsqrt_rn(dd);                // dd >= 0 already
            k2[r] = ((ull)__float_as_uint(dist) << 32) | (key[r] & 0xffffffffULL);
        }
        #pragma unroll
        for (int i = 0; i < KNN - 1; ++i)                     // bubble by (dist,idx)
            #pragma unroll
            for (int p = 0; p < KNN - 1 - i; ++p) {
                const ull lo = umin64(k2[p], k2[p + 1]);
                const ull hi = umax64(k2[p], k2[p + 1]);
                k2[p] = lo; k2[p + 1] = hi;
            }

        float nx[KNN], ny[KNN], nz[KNN];
        #pragma unroll
        for (int r = 0; r < KNN; ++r) {
            const int sel = (int)(k2[r] & 0xffffffffULL);
            nx[r] = batch[sel * 3 + 0];
            ny[r] = batch[sel * 3 + 1];
            nz[r] = batch[sel * 3 + 2];
        }
        float sx = nx[0], sy = ny[0], sz = nz[0];
        #pragma unroll
        for (int r = 1; r < KNN; ++r) {
            sx = __fadd_rn(sx, nx[r]);
            sy = __fadd_rn(sy, ny[r]);
            sz = __fadd_rn(sz, nz[r]);
        }
        const float cx = __fdiv_rn(sx, 5.0f);
        const float cy = __fdiv_rn(sy, 5.0f);
        const float cz = __fdiv_rn(sz, 5.0f);

        float sxx = 0.0f, syy = 0.0f, szz = 0.0f;
        #pragma unroll
        for (int r = 0; r < KNN; ++r) {
            const float dx = __fsub_rn(nx[r], cx);
            const float dy = __fsub_rn(ny[r], cy);
            const float dz = __fsub_rn(nz[r], cz);
            sxx = __fadd_rn(sxx, __fmul_rn(dx, dx));
            syy = __fadd_rn(syy, __fmul_rn(dy, dy));
            szz = __fadd_rn(szz, __fmul_rn(dz, dz));
        }
        const float trace = __fadd_rn(__fadd_rn(__fmul_rn(sxx, 0.25f),
                                                __fmul_rn(syy, 0.25f)),
                                      __fmul_rn(szz, 0.25f));
        const u32 oq = bi[qs];                                // query's orig idx
        trace_out[(size_t)b * N_PTS + oq] = trace;
    }
}

// ---------------- K3: r1-proven curvature normalize (in-place) ----------------
__global__ __launch_bounds__(256)
void curvature_kernel(float* __restrict__ io)
{
    __shared__ float red[256];
    const int b = blockIdx.x;
    const int t = threadIdx.x;
    float* __restrict__ tr = io + (size_t)b * N_PTS;

    float v[16];
    float s = 0.0f;
    #pragma unroll
    for (int i = 0; i < 16; ++i) {
        v[i] = tr[t + i * 256];
        s += v[i];
    }
    red[t] = s;
    __syncthreads();
    #pragma unroll
    for (int o = 128; o > 0; o >>= 1) {
        if (t < o) red[t] += red[t + o];
        __syncthreads();
    }
    const float denom = red[0] + 1e-8f;
    #pragma unroll
    for (int i = 0; i < 16; ++i)
        tr[t + i * 256] = v[i] / denom;
}

extern "C" void kernel_launch(void* const* d_in, const int* in_sizes, int n_in,
                              void* d_out, int out_size, void* d_ws, size_t ws_size,
                              hipStream_t stream)
{
    (void)in_sizes; (void)n_in; (void)out_size; (void)ws_size;
    const float* pcd = (const float*)d_in[0];   // [8,4096,3] f32
    float* out = (float*)d_out;                 // [8,4096] f32

    char* w = (char*)d_ws;
    float4* spts = (float4*)w;                          // 512 KB
    u16*    sidxp = (u16*)(w + 524288);                 // 64 KB
    u32*    table = (u32*)(w + 524288 + 65536);         // 8*130*4 B

    build_kernel<<<BATCH, 256, 0, stream>>>(pcd, spts, sidxp, table);
    dim3 g2(N_PTS / 32, BATCH);                         // 128 x 8 = 1024 blocks
    knn_kernel<<<g2, 64, 0, stream>>>(pcd, spts, sidxp, table, out);
    curvature_kernel<<<BATCH, 256, 0, stream>>>(out);
}